// Round 9
// baseline (339.722 us; speedup 1.0000x reference)
//
#include <hip/hip_runtime.h>

typedef unsigned short u16;
typedef __attribute__((ext_vector_type(8))) short short8;
typedef __attribute__((ext_vector_type(4))) float f32x4;
typedef __attribute__((ext_vector_type(16))) float f32x16;

#define AS1C(p) ((const __attribute__((address_space(1))) void*)(p))
#define AS3(p)  ((__attribute__((address_space(3))) void*)(p))

constexpr int CC    = 256;      // channels
constexpr int HWSZ  = 4096;     // H*W
constexpr int NNODE = 131072;   // B*H*W
constexpr int EEDG  = 524288;   // edges
constexpr int CAP   = 32;       // per-node bucket capacity

__device__ __forceinline__ float bf2f(u16 h){ unsigned u = ((unsigned)h)<<16; float f; __builtin_memcpy(&f,&u,4); return f; }
__device__ __forceinline__ u16 f2bf(float f){ unsigned u; __builtin_memcpy(&u,&f,4); return (u16)((u + 0x7FFFu + ((u>>16)&1u))>>16); }

// tanh-form GELU via native exp (max abs err vs exact ~3e-4)
__device__ __forceinline__ float gelu_fast(float v){
  float y = 0.7978845608f*(v + 0.044715f*v*v*v);
  float e = __expf(2.0f*y);
  float r = __builtin_amdgcn_rcpf(e + 1.0f);
  return 0.5f*v*(2.0f - 2.0f*r);
}

__device__ __forceinline__ void unpack8(uint4 q, float f[8]){
  unsigned w0=q.x,w1=q.y,w2=q.z,w3=q.w;
  unsigned l0=w0<<16, h0=w0&0xffff0000u, l1=w1<<16, h1=w1&0xffff0000u;
  unsigned l2=w2<<16, h2=w2&0xffff0000u, l3=w3<<16, h3=w3&0xffff0000u;
  __builtin_memcpy(&f[0],&l0,4); __builtin_memcpy(&f[1],&h0,4);
  __builtin_memcpy(&f[2],&l1,4); __builtin_memcpy(&f[3],&h1,4);
  __builtin_memcpy(&f[4],&l2,4); __builtin_memcpy(&f[5],&h2,4);
  __builtin_memcpy(&f[6],&l3,4); __builtin_memcpy(&f[7],&h3,4);
}

// ---------------- fp32 64x64 tiled transpose (weights only) ----------------
__global__ __launch_bounds__(256) void transpose_split(const float* __restrict__ src,
                                                       u16* __restrict__ dhi, u16* __restrict__ dlo,
                                                       int R, int Ccols, size_t sb_in, size_t sb_out)
{
  __shared__ float t[64][65];
  const float* s = src + blockIdx.z*sb_in + (size_t)(blockIdx.y*64)*Ccols + blockIdx.x*64;
  size_t obase   = blockIdx.z*sb_out + (size_t)(blockIdx.x*64)*R + blockIdx.y*64;
  int tid = threadIdx.x;
  for (int i=0;i<4;++i){
    int idx = i*256 + tid;
    int r = idx>>4, q = idx&15;
    float4 v = *(const float4*)(s + (size_t)r*Ccols + q*4);
    t[r][q*4+0]=v.x; t[r][q*4+1]=v.y; t[r][q*4+2]=v.z; t[r][q*4+3]=v.w;
  }
  __syncthreads();
  for (int i=0;i<2;++i){
    int idx = i*256 + tid;
    int rr = idx>>3, ch = idx&7;
    u16 hi[8], lo[8];
    for (int j=0;j<8;++j){
      float f = t[ch*8+j][rr];
      u16 h = f2bf(f); hi[j] = h;
      lo[j] = f2bf(f - bf2f(h));
    }
    *(uint4*)(dhi + obase + (size_t)rr*R + ch*8) = *(uint4*)hi;
    if (dlo) *(uint4*)(dlo + obase + (size_t)rr*R + ch*8) = *(uint4*)lo;
  }
}

// ---------------- GEMM1 (transpose-fused): x = imgT @ Wp + bp ----------------
// BM=64, BN=256 (4 waves x 64-col stripes). A loaded DIRECTLY to registers from
// img fp32 (lanes 0..31 read consecutive rows -> 128B sectors; no A-LDS, no
// scalar ds_reads), packed to bf16 via v_perm. One-step A prefetch (arA/arB,
// static alternation). B double-buffered via global_load_lds. LDS 32KB.
__global__ __launch_bounds__(256,3) void gemm_img(const float* __restrict__ img,
                                                  const u16* __restrict__ Bt,
                                                  const float* __restrict__ bias,
                                                  u16* __restrict__ C)
{
  __shared__ u16 Bs[2][256*32];
  const int tid = threadIdx.x, wid = tid>>6, lane = tid&63;
  const int row0 = blockIdx.x*64;
  const int bb = row0 >> 12, hw0 = row0 & 4095;
  const float* abase = img + (size_t)bb*CC*HWSZ + hw0;
  const int l31 = lane&31, lh = lane>>5;

  f32x16 acc[2][2];
  #pragma unroll
  for (int i=0;i<2;++i)
    #pragma unroll
    for (int j=0;j<2;++j)
      #pragma unroll
      for (int e=0;e<16;++e) acc[i][j][e]=0.f;

  float arA[32], arB[32];   // [fm*16 + kh*8 + j]

#define LOADA(dst, kt)                                                                  \
  { _Pragma("unroll")                                                                   \
    for (int fm=0; fm<2; ++fm)                                                          \
      _Pragma("unroll")                                                                 \
      for (int kh=0; kh<2; ++kh)                                                        \
        _Pragma("unroll")                                                               \
        for (int j=0; j<8; ++j)                                                         \
          dst[fm*16+kh*8+j] =                                                           \
            abase[(size_t)((kt)+kh*16+lh*8+j)*HWSZ + fm*32 + l31]; }

#define STAGE_B(buf, kt)                                                                \
  { _Pragma("unroll")                                                                   \
    for (int it=0; it<4; ++it){                                                         \
      int qb = (it*4+wid)*64;                                                           \
      int q  = qb + lane;                                                               \
      int m  = q>>2, sc = q&3;                                                          \
      int gs = sc ^ ((m>>1)&3);                                                         \
      __builtin_amdgcn_global_load_lds(AS1C(Bt + (size_t)m*256 + (kt) + gs*8),          \
                                       AS3(&Bs[buf][qb*8]), 16, 0, 0); } }

#define STEP(t, CUR, NXT)                                                               \
  { const int cur = (t)&1;                                                              \
    if ((t) < 7) { STAGE_B(cur^1, ((t)+1)*32) LOADA(NXT, ((t)+1)*32) }                  \
    short8 ah[2][2], bfr[2][2];                                                         \
    _Pragma("unroll")                                                                   \
    for (int fm=0; fm<2; ++fm)                                                          \
      _Pragma("unroll")                                                                 \
      for (int kh=0; kh<2; ++kh) {                                                      \
        unsigned w[4];                                                                  \
        _Pragma("unroll")                                                               \
        for (int p=0; p<4; ++p) {                                                       \
          unsigned u0, u1;                                                              \
          float f0 = CUR[fm*16+kh*8+2*p];                                               \
          float f1 = CUR[fm*16+kh*8+2*p+1];                                             \
          __builtin_memcpy(&u0,&f0,4); __builtin_memcpy(&u1,&f1,4);                     \
          w[p] = __builtin_amdgcn_perm(u1, u0, 0x07060302u);                            \
        }                                                                               \
        __builtin_memcpy(&ah[fm][kh], w, 16);                                           \
      }                                                                                 \
    _Pragma("unroll")                                                                   \
    for (int fn=0; fn<2; ++fn)                                                          \
      _Pragma("unroll")                                                                 \
      for (int kh=0; kh<2; ++kh) {                                                      \
        int col = wid*64 + fn*32 + l31;                                                 \
        int sb  = (kh*2 + lh) ^ ((col>>1)&3);                                           \
        bfr[fn][kh] = *(const short8*)&Bs[cur][col*32 + sb*8];                          \
      }                                                                                 \
    _Pragma("unroll")                                                                   \
    for (int kh=0; kh<2; ++kh)                                                          \
      _Pragma("unroll")                                                                 \
      for (int fm=0; fm<2; ++fm)                                                        \
        _Pragma("unroll")                                                               \
        for (int fn=0; fn<2; ++fn)                                                      \
          acc[fm][fn] = __builtin_amdgcn_mfma_f32_32x32x16_bf16(ah[fm][kh], bfr[fn][kh], acc[fm][fn], 0, 0, 0); \
    asm volatile("s_waitcnt vmcnt(0)" ::: "memory");                                    \
    __syncthreads(); }

  LOADA(arA, 0)
  STAGE_B(0, 0)
  asm volatile("s_waitcnt vmcnt(0)" ::: "memory");
  __syncthreads();

  for (int tt=0; tt<8; tt+=2) {
    STEP(tt,   arA, arB)
    STEP(tt+1, arB, arA)
  }
#undef STEP
#undef STAGE_B
#undef LOADA

  #pragma unroll
  for (int fn=0; fn<2; ++fn) {
    int col = wid*64 + fn*32 + l31;
    float bv = bias ? bias[col] : 0.f;
    #pragma unroll
    for (int fm=0; fm<2; ++fm) {
      int rbase = row0 + fm*32 + 4*lh;
      #pragma unroll
      for (int reg=0; reg<16; ++reg) {
        int row = rbase + (reg&3) + 8*(reg>>2);
        C[(size_t)row*256 + col] = f2bf(acc[fm][fn][reg] + bv);
      }
    }
  }
}

// ---------------- GEMM2: xl = x @ Wg  (A direct-to-reg 16B loads, B dbuf LDS) ----------------
__global__ __launch_bounds__(256,3) void gemm1p(const u16* __restrict__ A,
                                                const u16* __restrict__ Bt,
                                                u16* __restrict__ C)
{
  __shared__ u16 Bs[2][256*32];
  const int tid = threadIdx.x, wid = tid>>6, lane = tid&63;
  const int row0 = blockIdx.x*64;
  const int l31 = lane&31, lh = lane>>5;

  f32x16 acc[2][2];
  #pragma unroll
  for (int i=0;i<2;++i)
    #pragma unroll
    for (int j=0;j<2;++j)
      #pragma unroll
      for (int e=0;e<16;++e) acc[i][j][e]=0.f;

  uint4 aA[4], aB[4];   // [fm*2 + kh] = 8 bf16 of A[row0+fm*32+l31, kt + (kh*2+lh)*8 ..]

#define LOADA1(dst, kt)                                                                 \
  { _Pragma("unroll")                                                                   \
    for (int fm=0; fm<2; ++fm)                                                          \
      _Pragma("unroll")                                                                 \
      for (int kh=0; kh<2; ++kh)                                                        \
        dst[fm*2+kh] = *(const uint4*)(A + (size_t)(row0+fm*32+l31)*256 + (kt) + (kh*2+lh)*8); }

#define STAGE_B(buf, kt)                                                                \
  { _Pragma("unroll")                                                                   \
    for (int it=0; it<4; ++it){                                                         \
      int qb = (it*4+wid)*64;                                                           \
      int q  = qb + lane;                                                               \
      int m  = q>>2, sc = q&3;                                                          \
      int gs = sc ^ ((m>>1)&3);                                                         \
      __builtin_amdgcn_global_load_lds(AS1C(Bt + (size_t)m*256 + (kt) + gs*8),          \
                                       AS3(&Bs[buf][qb*8]), 16, 0, 0); } }

#define STEP(t, CUR, NXT)                                                               \
  { const int cur = (t)&1;                                                              \
    if ((t) < 7) { STAGE_B(cur^1, ((t)+1)*32) LOADA1(NXT, ((t)+1)*32) }                 \
    short8 af[2][2], bfr[2][2];                                                         \
    _Pragma("unroll")                                                                   \
    for (int fm=0; fm<2; ++fm)                                                          \
      _Pragma("unroll")                                                                 \
      for (int kh=0; kh<2; ++kh)                                                        \
        __builtin_memcpy(&af[fm][kh], &CUR[fm*2+kh], 16);                               \
    _Pragma("unroll")                                                                   \
    for (int fn=0; fn<2; ++fn)                                                          \
      _Pragma("unroll")                                                                 \
      for (int kh=0; kh<2; ++kh) {                                                      \
        int col = wid*64 + fn*32 + l31;                                                 \
        int sb  = (kh*2 + lh) ^ ((col>>1)&3);                                           \
        bfr[fn][kh] = *(const short8*)&Bs[cur][col*32 + sb*8];                          \
      }                                                                                 \
    _Pragma("unroll")                                                                   \
    for (int kh=0; kh<2; ++kh)                                                          \
      _Pragma("unroll")                                                                 \
      for (int fm=0; fm<2; ++fm)                                                        \
        _Pragma("unroll")                                                               \
        for (int fn=0; fn<2; ++fn)                                                      \
          acc[fm][fn] = __builtin_amdgcn_mfma_f32_32x32x16_bf16(af[fm][kh], bfr[fn][kh], acc[fm][fn], 0, 0, 0); \
    asm volatile("s_waitcnt vmcnt(0)" ::: "memory");                                    \
    __syncthreads(); }

  LOADA1(aA, 0)
  STAGE_B(0, 0)
  asm volatile("s_waitcnt vmcnt(0)" ::: "memory");
  __syncthreads();

  for (int tt=0; tt<8; tt+=2) {
    STEP(tt,   aA, aB)
    STEP(tt+1, aB, aA)
  }
#undef STEP
#undef STAGE_B
#undef LOADA1

  #pragma unroll
  for (int fn=0; fn<2; ++fn) {
    int col = wid*64 + fn*32 + l31;
    #pragma unroll
    for (int fm=0; fm<2; ++fm) {
      int rbase = row0 + fm*32 + 4*lh;
      #pragma unroll
      for (int reg=0; reg<16; ++reg) {
        int row = rbase + (reg&3) + 8*(reg>>2);
        C[(size_t)row*256 + col] = f2bf(acc[fm][fn][reg]);
      }
    }
  }
}

// ---------------- graph prep ----------------
__global__ void fill_all(const int* __restrict__ row, const int* __restrict__ col,
                         int* __restrict__ cur, int* __restrict__ bucket){
  int e = blockIdx.x*256 + threadIdx.x;
  if (e >= EEDG) return;
  int c = col[e];
  int s = atomicAdd(&cur[c], 1);
  if (s < CAP) bucket[(size_t)c*CAP + s] = row[e];
}
__global__ void calc_dinv(const int* __restrict__ cnt, float* __restrict__ dinv){
  int n = blockIdx.x*256 + threadIdx.x;
  if (n < NNODE) dinv[n] = rsqrtf((float)cnt[n] + 1.0f);
}

// ---------------- fused: aggregate + bg + GELU + residual + LN + head logits ----------------
__global__ __launch_bounds__(256) void fused_agg(
    const u16* __restrict__ xl, const u16* __restrict__ xhi,
    const int* __restrict__ cnt, const float* __restrict__ dinv, const int* __restrict__ bucket,
    const float* __restrict__ bgv, const float* __restrict__ gam, const float* __restrict__ bet,
    const float* __restrict__ qv, float* __restrict__ outg, float* __restrict__ logits)
{
  const int wid = threadIdx.x>>6, lane = threadIdx.x&63;
  const int half = lane>>5, sl = lane&31;
  const int n = blockIdx.x*8 + wid*2 + half;
  const int c0 = sl*8;
  const float dn = dinv[n];
  int lim = cnt[n]; if (lim > CAP) lim = CAP;

  int rl = bucket[(size_t)n*CAP + sl];
  if (sl >= lim) rl = n;                 // sanitize poison slots
  float wl = (sl < lim) ? dinv[rl]*dn : 0.0f;

  uint4 qh = *(const uint4*)(xhi + (size_t)n*256 + c0);

  float a[8];
  {
    uint4 q = *(const uint4*)(xl + (size_t)n*256 + c0);
    unpack8(q, a);
    float wself = dn*dn;
    #pragma unroll
    for (int j=0;j<8;++j) a[j] *= wself;
  }

  int limR = (lim + 3) & ~3;
  for (int s=0; s<limR; s+=4) {
    int b0 = half*32 + s;
    int  r0 = __shfl(rl, b0),   r1 = __shfl(rl, b0+1);
    int  r2 = __shfl(rl, b0+2), r3 = __shfl(rl, b0+3);
    float w0 = __shfl(wl, b0),   w1 = __shfl(wl, b0+1);
    float w2 = __shfl(wl, b0+2), w3 = __shfl(wl, b0+3);
    uint4 q0 = *(const uint4*)(xl + (size_t)r0*256 + c0);
    uint4 q1 = *(const uint4*)(xl + (size_t)r1*256 + c0);
    uint4 q2 = *(const uint4*)(xl + (size_t)r2*256 + c0);
    uint4 q3 = *(const uint4*)(xl + (size_t)r3*256 + c0);
    float f0[8], f1[8], f2[8], f3[8];
    unpack8(q0, f0); unpack8(q1, f1); unpack8(q2, f2); unpack8(q3, f3);
    #pragma unroll
    for (int j=0;j<8;++j) a[j] += f0[j]*w0 + f1[j]*w1 + f2[j]*w2 + f3[j]*w3;
  }

  float xv[8];
  unpack8(qh, xv);

  float4 b0v = *(const float4*)(bgv + c0), b1v = *(const float4*)(bgv + c0 + 4);
  float bgs[8] = {b0v.x,b0v.y,b0v.z,b0v.w,b1v.x,b1v.y,b1v.z,b1v.w};
  float g[8];
  float s1 = 0.f, s2 = 0.f;
  #pragma unroll
  for (int j=0;j<8;++j){
    g[j] = gelu_fast(a[j] + bgs[j]) + xv[j];
    s1 += g[j]; s2 += g[j]*g[j];
  }
  #pragma unroll
  for (int off=16; off; off>>=1){ s1 += __shfl_xor(s1, off); s2 += __shfl_xor(s2, off); }
  float mu  = s1*(1.0f/256.0f);
  float var = s2*(1.0f/256.0f) - mu*mu;
  float inv = rsqrtf(var + 1e-5f);

  float4 g0 = *(const float4*)(gam + c0), g1 = *(const float4*)(gam + c0 + 4);
  float4 e0 = *(const float4*)(bet + c0), e1 = *(const float4*)(bet + c0 + 4);
  float gms[8] = {g0.x,g0.y,g0.z,g0.w,g1.x,g1.y,g1.z,g1.w};
  float bts[8] = {e0.x,e0.y,e0.z,e0.w,e1.x,e1.y,e1.z,e1.w};
  float y[8];
  #pragma unroll
  for (int j=0;j<8;++j) y[j] = (g[j]-mu)*inv*gms[j] + bts[j];

  float4 o0 = {y[0],y[1],y[2],y[3]}, o1 = {y[4],y[5],y[6],y[7]};
  *reinterpret_cast<float4*>(outg + (size_t)n*256 + c0)     = o0;
  *reinterpret_cast<float4*>(outg + (size_t)n*256 + c0 + 4) = o1;

  float4 q0 = *(const float4*)(qv + c0), q1 = *(const float4*)(qv + c0 + 4);
  float qs[8] = {q0.x,q0.y,q0.z,q0.w,q1.x,q1.y,q1.z,q1.w};
  float dq = 0.f;
  #pragma unroll
  for (int j=0;j<8;++j) dq += y[j]*qs[j];
  dq += __shfl_xor(dq,1); dq += __shfl_xor(dq,2);
  if ((sl&3)==0){
    int b = n>>12, p = n&4095, h = sl>>2;
    logits[(size_t)(b*8+h)*4096 + p] = dq*10.0f;   // 1/TEMPERATURE
  }
}

// ---------------- row softmax over 4096 (fp32 in/out) ----------------
__global__ __launch_bounds__(256) void softmax_rows(const float* __restrict__ logits, float* __restrict__ outa){
  int r = blockIdx.x;
  const float* p = logits + (size_t)r*4096;
  int tid = threadIdx.x;
  int wid = tid>>6, lane = tid&63;
  __shared__ float redm[4];
  __shared__ float reds[4];
  float v[16];
  float mx = -1e30f;
  for (int i=0;i<16;++i){ v[i] = p[tid + i*256]; mx = fmaxf(mx, v[i]); }
  for (int off=32; off; off>>=1) mx = fmaxf(mx, __shfl_xor(mx, off));
  if (lane==0) redm[wid]=mx;
  __syncthreads();
  mx = fmaxf(fmaxf(redm[0],redm[1]), fmaxf(redm[2],redm[3]));
  float sum = 0.f;
  for (int i=0;i<16;++i){ v[i] = expf(v[i]-mx); sum += v[i]; }
  for (int off=32; off; off>>=1) sum += __shfl_xor(sum, off);
  if (lane==0) reds[wid]=sum;
  __syncthreads();
  sum = reds[0]+reds[1]+reds[2]+reds[3];
  float rinv = 1.0f/sum;
  for (int i=0;i<16;++i) outa[(size_t)r*4096 + tid + i*256] = v[i]*rinv;
}

extern "C" void kernel_launch(void* const* d_in, const int* in_sizes, int n_in,
                              void* d_out, int out_size, void* d_ws, size_t ws_size,
                              hipStream_t stream)
{
  const float* img  = (const float*)d_in[0];
  const int* edges  = (const int*)d_in[1];   // [2][E] int32: row=edges, col=edges+E
  const float* Wp   = (const float*)d_in[2];
  const float* bp   = (const float*)d_in[3];
  const float* Wg   = (const float*)d_in[4];
  const float* bg   = (const float*)d_in[5];
  const float* lng  = (const float*)d_in[6];
  const float* lnb  = (const float*)d_in[7];
  const float* dq   = (const float*)d_in[8];
  char* ws = (char*)d_ws;

  constexpr size_t REG  = (size_t)NNODE*CC*2;                                   // 67,108,864
  constexpr size_t WTS  = 2u*131072;
  constexpr size_t GBLK = 524288u*2 + (size_t)NNODE*CAP*4 + (size_t)256*4096*4; // ~21.8 MB
  if (ws_size < 2*REG + WTS + GBLK) return;

  u16* x_hi = (u16*)(ws + 0);
  u16* xl   = (u16*)(ws + REG);
  char* wts  = ws + 2*REG;
  char* gblk = wts + WTS;

  u16* WpT_hi = (u16*)(wts);
  u16* WgT_hi = (u16*)(wts + 131072);
  int*   cur    = (int*)(gblk);
  float* dinv   = (float*)(gblk + 524288);
  int*   bucket = (int*)(gblk + 1048576);
  float* logits = (float*)(gblk + 1048576 + (size_t)NNODE*CAP*4);

  // weight transposes (tiny, hi only)
  transpose_split<<<dim3(4,4,1), 256, 0, stream>>>(Wp, WpT_hi, nullptr, 256, 256, 0, 0);
  transpose_split<<<dim3(4,4,1), 256, 0, stream>>>(Wg, WgT_hi, nullptr, 256, 256, 0, 0);

  // graph prep
  hipMemsetAsync(cur, 0, 524288, stream);
  fill_all <<<2048, 256, 0, stream>>>(edges, edges+EEDG, cur, bucket);
  calc_dinv<<<512,  256, 0, stream>>>(cur, dinv);

  // x = imgT @ Wp + bp   (transpose fused, A direct-to-reg)
  gemm_img<<<2048, 256, 0, stream>>>(img, WpT_hi, bp, x_hi);
  // xl = x @ Wg          (A direct-to-reg)
  gemm1p<<<2048, 256, 0, stream>>>(x_hi, WgT_hi, xl);

  float* outg = (float*)d_out;
  float* outa = (float*)d_out + (size_t)NNODE*CC;
  fused_agg<<<NNODE/8, 256, 0, stream>>>(xl, x_hi, cur, dinv, bucket,
                                         bg, lng, lnb, dq, outg, logits);
  softmax_rows<<<256, 256, 0, stream>>>(logits, outa);
}

// Round 10
// 242.591 us; speedup vs baseline: 1.4004x; 1.4004x over previous
//
#include <hip/hip_runtime.h>

typedef unsigned short u16;
typedef __attribute__((ext_vector_type(8))) short short8;
typedef __attribute__((ext_vector_type(16))) float f32x16;

#define AS1C(p) ((const __attribute__((address_space(1))) void*)(p))
#define AS3(p)  ((__attribute__((address_space(3))) void*)(p))

constexpr int CC    = 256;      // channels
constexpr int HWSZ  = 4096;     // H*W
constexpr int NNODE = 131072;   // B*H*W
constexpr int EEDG  = 524288;   // edges
constexpr int CAP   = 32;      // per-node bucket capacity

__device__ __forceinline__ float bf2f(u16 h){ unsigned u = ((unsigned)h)<<16; float f; __builtin_memcpy(&f,&u,4); return f; }
__device__ __forceinline__ u16 f2bf(float f){ unsigned u; __builtin_memcpy(&u,&f,4); return (u16)((u + 0x7FFFu + ((u>>16)&1u))>>16); }

// tanh-form GELU via native exp (max abs err vs exact ~3e-4)
__device__ __forceinline__ float gelu_fast(float v){
  float y = 0.7978845608f*(v + 0.044715f*v*v*v);
  float e = __expf(2.0f*y);
  float r = __builtin_amdgcn_rcpf(e + 1.0f);
  return 0.5f*v*(2.0f - 2.0f*r);
}

__device__ __forceinline__ void unpack8(uint4 q, float f[8]){
  unsigned w0=q.x,w1=q.y,w2=q.z,w3=q.w;
  unsigned l0=w0<<16, h0=w0&0xffff0000u, l1=w1<<16, h1=w1&0xffff0000u;
  unsigned l2=w2<<16, h2=w2&0xffff0000u, l3=w3<<16, h3=w3&0xffff0000u;
  __builtin_memcpy(&f[0],&l0,4); __builtin_memcpy(&f[1],&h0,4);
  __builtin_memcpy(&f[2],&l1,4); __builtin_memcpy(&f[3],&h1,4);
  __builtin_memcpy(&f[4],&l2,4); __builtin_memcpy(&f[5],&h2,4);
  __builtin_memcpy(&f[6],&l3,4); __builtin_memcpy(&f[7],&h3,4);
}

// ---------------- fp32 64x64 tiled transpose -> bf16 hi (+ optional lo) ----------------
__global__ __launch_bounds__(256) void transpose_split(const float* __restrict__ src,
                                                       u16* __restrict__ dhi, u16* __restrict__ dlo,
                                                       int R, int Ccols, size_t sb_in, size_t sb_out)
{
  __shared__ float t[64][65];
  const float* s = src + blockIdx.z*sb_in + (size_t)(blockIdx.y*64)*Ccols + blockIdx.x*64;
  size_t obase   = blockIdx.z*sb_out + (size_t)(blockIdx.x*64)*R + blockIdx.y*64;
  int tid = threadIdx.x;
  for (int i=0;i<4;++i){
    int idx = i*256 + tid;
    int r = idx>>4, q = idx&15;
    float4 v = *(const float4*)(s + (size_t)r*Ccols + q*4);
    t[r][q*4+0]=v.x; t[r][q*4+1]=v.y; t[r][q*4+2]=v.z; t[r][q*4+3]=v.w;
  }
  __syncthreads();
  for (int i=0;i<2;++i){
    int idx = i*256 + tid;
    int rr = idx>>3, ch = idx&7;
    u16 hi[8], lo[8];
    for (int j=0;j<8;++j){
      float f = t[ch*8+j][rr];
      u16 h = f2bf(f); hi[j] = h;
      lo[j] = f2bf(f - bf2f(h));
    }
    *(uint4*)(dhi + obase + (size_t)rr*R + ch*8) = *(uint4*)hi;
    if (dlo) *(uint4*)(dlo + obase + (size_t)rr*R + ch*8) = *(uint4*)lo;
  }
}

// ---------------- GEMM template: C = A @ BtT + bias  (BM=64, BN=256, 1-product) ----------------
// A [M,256] bf16 K-contig; Bt [256,256] bf16 (Bt[n][k] = B[k][n]).
// 4 waves x 64-col stripes; A+B staged via global_load_lds (16B) with XOR chunk
// swizzle; fragments via ds_read_b128; 32x32x16 MFMA; 2-phase dbuf. (R8-proven, ~27us)
__global__ __launch_bounds__(256,3) void gemm1p(const u16* __restrict__ A,
                                                const u16* __restrict__ Bt,
                                                const float* __restrict__ bias,
                                                u16* __restrict__ C)
{
  __shared__ u16 As[2][64*32];
  __shared__ u16 Bs[2][256*32];
  const int tid = threadIdx.x, wid = tid>>6, lane = tid&63;
  const int row0 = blockIdx.x*64;
  const int l31 = lane&31, lh = lane>>5;

  f32x16 acc[2][2];
  #pragma unroll
  for (int i=0;i<2;++i)
    #pragma unroll
    for (int j=0;j<2;++j)
      #pragma unroll
      for (int e=0;e<16;++e) acc[i][j][e]=0.f;

#define STAGE_AB(buf, kt)                                                              \
  {                                                                                    \
    {                                                                                  \
      int qb = wid*64;                                                                 \
      int q  = qb + lane;                                                              \
      int m  = q>>2, sc = q&3;                                                         \
      int gs = sc ^ ((m>>1)&3);                                                        \
      __builtin_amdgcn_global_load_lds(AS1C(A + (size_t)(row0+m)*256 + (kt) + gs*8),   \
                                       AS3(&As[buf][qb*8]), 16, 0, 0);                 \
    }                                                                                  \
    _Pragma("unroll")                                                                  \
    for (int it=0; it<4; ++it){                                                        \
      int qb = (it*4+wid)*64;                                                          \
      int q  = qb + lane;                                                              \
      int m  = q>>2, sc = q&3;                                                         \
      int gs = sc ^ ((m>>1)&3);                                                        \
      __builtin_amdgcn_global_load_lds(AS1C(Bt + (size_t)m*256 + (kt) + gs*8),         \
                                       AS3(&Bs[buf][qb*8]), 16, 0, 0);                 \
    }                                                                                  \
  }

  STAGE_AB(0, 0)
  asm volatile("s_waitcnt vmcnt(0)" ::: "memory");
  __syncthreads();

  for (int t=0; t<8; ++t) {
    int cur = t&1;
    if (t<7) STAGE_AB(cur^1, (t+1)*32)

    short8 af[2][2], bfr[2][2];
    #pragma unroll
    for (int fm=0; fm<2; ++fm)
      #pragma unroll
      for (int kh=0; kh<2; ++kh) {
        int row = fm*32 + l31;
        int sa  = (kh*2 + lh) ^ ((row>>1)&3);
        af[fm][kh] = *(const short8*)&As[cur][row*32 + sa*8];
      }
    #pragma unroll
    for (int fn=0; fn<2; ++fn)
      #pragma unroll
      for (int kh=0; kh<2; ++kh) {
        int col = wid*64 + fn*32 + l31;
        int sb  = (kh*2 + lh) ^ ((col>>1)&3);
        bfr[fn][kh] = *(const short8*)&Bs[cur][col*32 + sb*8];
      }
    #pragma unroll
    for (int kh=0; kh<2; ++kh)
      #pragma unroll
      for (int fm=0; fm<2; ++fm)
        #pragma unroll
        for (int fn=0; fn<2; ++fn)
          acc[fm][fn] = __builtin_amdgcn_mfma_f32_32x32x16_bf16(af[fm][kh], bfr[fn][kh], acc[fm][fn], 0, 0, 0);
    asm volatile("s_waitcnt vmcnt(0)" ::: "memory");
    __syncthreads();
  }
#undef STAGE_AB

  #pragma unroll
  for (int fn=0; fn<2; ++fn) {
    int col = wid*64 + fn*32 + l31;
    float bv = bias ? bias[col] : 0.f;
    #pragma unroll
    for (int fm=0; fm<2; ++fm) {
      int rbase = row0 + fm*32 + 4*lh;
      #pragma unroll
      for (int reg=0; reg<16; ++reg) {
        int row = rbase + (reg&3) + 8*(reg>>2);
        C[(size_t)row*256 + col] = f2bf(acc[fm][fn][reg] + bv);
      }
    }
  }
}

// ---------------- graph prep ----------------
__global__ void fill_all(const int* __restrict__ row, const int* __restrict__ col,
                         int* __restrict__ cur, int* __restrict__ bucket){
  int e = blockIdx.x*256 + threadIdx.x;
  if (e >= EEDG) return;
  int c = col[e];
  int s = atomicAdd(&cur[c], 1);
  if (s < CAP) bucket[(size_t)c*CAP + s] = row[e];
}
__global__ void calc_dinv(const int* __restrict__ cnt, float* __restrict__ dinv){
  int n = blockIdx.x*256 + threadIdx.x;
  if (n < NNODE) dinv[n] = rsqrtf((float)cnt[n] + 1.0f);
}

// ---------------- fused: aggregate + bg + GELU + residual + LN + head logits ----------------
__global__ __launch_bounds__(256) void fused_agg(
    const u16* __restrict__ xl, const u16* __restrict__ xhi,
    const int* __restrict__ cnt, const float* __restrict__ dinv, const int* __restrict__ bucket,
    const float* __restrict__ bgv, const float* __restrict__ gam, const float* __restrict__ bet,
    const float* __restrict__ qv, float* __restrict__ outg, float* __restrict__ logits)
{
  const int wid = threadIdx.x>>6, lane = threadIdx.x&63;
  const int half = lane>>5, sl = lane&31;
  const int n = blockIdx.x*8 + wid*2 + half;
  const int c0 = sl*8;
  const float dn = dinv[n];
  int lim = cnt[n]; if (lim > CAP) lim = CAP;

  int rl = bucket[(size_t)n*CAP + sl];
  if (sl >= lim) rl = n;                 // sanitize poison slots
  float wl = (sl < lim) ? dinv[rl]*dn : 0.0f;

  uint4 qh = *(const uint4*)(xhi + (size_t)n*256 + c0);

  float a[8];
  {
    uint4 q = *(const uint4*)(xl + (size_t)n*256 + c0);
    unpack8(q, a);
    float wself = dn*dn;
    #pragma unroll
    for (int j=0;j<8;++j) a[j] *= wself;
  }

  int limR = (lim + 3) & ~3;
  for (int s=0; s<limR; s+=4) {
    int b0 = half*32 + s;
    int  r0 = __shfl(rl, b0),   r1 = __shfl(rl, b0+1);
    int  r2 = __shfl(rl, b0+2), r3 = __shfl(rl, b0+3);
    float w0 = __shfl(wl, b0),   w1 = __shfl(wl, b0+1);
    float w2 = __shfl(wl, b0+2), w3 = __shfl(wl, b0+3);
    uint4 q0 = *(const uint4*)(xl + (size_t)r0*256 + c0);
    uint4 q1 = *(const uint4*)(xl + (size_t)r1*256 + c0);
    uint4 q2 = *(const uint4*)(xl + (size_t)r2*256 + c0);
    uint4 q3 = *(const uint4*)(xl + (size_t)r3*256 + c0);
    float f0[8], f1[8], f2[8], f3[8];
    unpack8(q0, f0); unpack8(q1, f1); unpack8(q2, f2); unpack8(q3, f3);
    #pragma unroll
    for (int j=0;j<8;++j) a[j] += f0[j]*w0 + f1[j]*w1 + f2[j]*w2 + f3[j]*w3;
  }

  float xv[8];
  unpack8(qh, xv);

  float4 b0v = *(const float4*)(bgv + c0), b1v = *(const float4*)(bgv + c0 + 4);
  float bgs[8] = {b0v.x,b0v.y,b0v.z,b0v.w,b1v.x,b1v.y,b1v.z,b1v.w};
  float g[8];
  float s1 = 0.f, s2 = 0.f;
  #pragma unroll
  for (int j=0;j<8;++j){
    g[j] = gelu_fast(a[j] + bgs[j]) + xv[j];
    s1 += g[j]; s2 += g[j]*g[j];
  }
  #pragma unroll
  for (int off=16; off; off>>=1){ s1 += __shfl_xor(s1, off); s2 += __shfl_xor(s2, off); }
  float mu  = s1*(1.0f/256.0f);
  float var = s2*(1.0f/256.0f) - mu*mu;
  float inv = rsqrtf(var + 1e-5f);

  float4 g0 = *(const float4*)(gam + c0), g1 = *(const float4*)(gam + c0 + 4);
  float4 e0 = *(const float4*)(bet + c0), e1 = *(const float4*)(bet + c0 + 4);
  float gms[8] = {g0.x,g0.y,g0.z,g0.w,g1.x,g1.y,g1.z,g1.w};
  float bts[8] = {e0.x,e0.y,e0.z,e0.w,e1.x,e1.y,e1.z,e1.w};
  float y[8];
  #pragma unroll
  for (int j=0;j<8;++j) y[j] = (g[j]-mu)*inv*gms[j] + bts[j];

  float4 o0 = {y[0],y[1],y[2],y[3]}, o1 = {y[4],y[5],y[6],y[7]};
  *reinterpret_cast<float4*>(outg + (size_t)n*256 + c0)     = o0;
  *reinterpret_cast<float4*>(outg + (size_t)n*256 + c0 + 4) = o1;

  float4 q0 = *(const float4*)(qv + c0), q1 = *(const float4*)(qv + c0 + 4);
  float qs[8] = {q0.x,q0.y,q0.z,q0.w,q1.x,q1.y,q1.z,q1.w};
  float dq = 0.f;
  #pragma unroll
  for (int j=0;j<8;++j) dq += y[j]*qs[j];
  dq += __shfl_xor(dq,1); dq += __shfl_xor(dq,2);
  if ((sl&3)==0){
    int b = n>>12, p = n&4095, h = sl>>2;
    logits[(size_t)(b*8+h)*4096 + p] = dq*10.0f;   // 1/TEMPERATURE
  }
}

// ---------------- row softmax over 4096 (fp32 in/out) ----------------
__global__ __launch_bounds__(256) void softmax_rows(const float* __restrict__ logits, float* __restrict__ outa){
  int r = blockIdx.x;
  const float* p = logits + (size_t)r*4096;
  int tid = threadIdx.x;
  int wid = tid>>6, lane = tid&63;
  __shared__ float redm[4];
  __shared__ float reds[4];
  float v[16];
  float mx = -1e30f;
  for (int i=0;i<16;++i){ v[i] = p[tid + i*256]; mx = fmaxf(mx, v[i]); }
  for (int off=32; off; off>>=1) mx = fmaxf(mx, __shfl_xor(mx, off));
  if (lane==0) redm[wid]=mx;
  __syncthreads();
  mx = fmaxf(fmaxf(redm[0],redm[1]), fmaxf(redm[2],redm[3]));
  float sum = 0.f;
  for (int i=0;i<16;++i){ v[i] = expf(v[i]-mx); sum += v[i]; }
  for (int off=32; off; off>>=1) sum += __shfl_xor(sum, off);
  if (lane==0) reds[wid]=sum;
  __syncthreads();
  sum = reds[0]+reds[1]+reds[2]+reds[3];
  float rinv = 1.0f/sum;
  for (int i=0;i<16;++i) outa[(size_t)r*4096 + tid + i*256] = v[i]*rinv;
}

extern "C" void kernel_launch(void* const* d_in, const int* in_sizes, int n_in,
                              void* d_out, int out_size, void* d_ws, size_t ws_size,
                              hipStream_t stream)
{
  const float* img  = (const float*)d_in[0];
  const int* edges  = (const int*)d_in[1];   // [2][E] int32: row=edges, col=edges+E
  const float* Wp   = (const float*)d_in[2];
  const float* bp   = (const float*)d_in[3];
  const float* Wg   = (const float*)d_in[4];
  const float* bg   = (const float*)d_in[5];
  const float* lng  = (const float*)d_in[6];
  const float* lnb  = (const float*)d_in[7];
  const float* dq   = (const float*)d_in[8];
  char* ws = (char*)d_ws;

  constexpr size_t REG  = (size_t)NNODE*CC*2;                                   // 67,108,864
  constexpr size_t WTS  = 2u*131072;
  constexpr size_t GBLK = 524288u*2 + (size_t)NNODE*CAP*4 + (size_t)256*4096*4; // ~21.8 MB
  if (ws_size < 2*REG + WTS + GBLK) return;

  u16* buf0 = (u16*)(ws + 0);        // x_hi
  u16* buf1 = (u16*)(ws + REG);      // imgT, then xl (imgT dead after GEMM1)
  char* wts  = ws + 2*REG;
  char* gblk = wts + WTS;

  u16* WpT_hi = (u16*)(wts);
  u16* WgT_hi = (u16*)(wts + 131072);
  int*   cur    = (int*)(gblk);
  float* dinv   = (float*)(gblk + 524288);
  int*   bucket = (int*)(gblk + 1048576);
  float* logits = (float*)(gblk + 1048576 + (size_t)NNODE*CAP*4);

  // weight transposes (tiny, hi only)
  transpose_split<<<dim3(4,4,1), 256, 0, stream>>>(Wp, WpT_hi, nullptr, 256, 256, 0, 0);
  transpose_split<<<dim3(4,4,1), 256, 0, stream>>>(Wg, WgT_hi, nullptr, 256, 256, 0, 0);

  // img -> imgT bf16 (hi only)
  transpose_split<<<dim3(64,4,32), 256, 0, stream>>>(img, buf1, nullptr, 256, 4096,
                                                     (size_t)CC*HWSZ, (size_t)HWSZ*CC);

  // graph prep
  hipMemsetAsync(cur, 0, 524288, stream);
  fill_all <<<2048, 256, 0, stream>>>(edges, edges+EEDG, cur, bucket);
  calc_dinv<<<512,  256, 0, stream>>>(cur, dinv);

  // x = imgT @ Wp + bp
  gemm1p<<<2048, 256, 0, stream>>>(buf1, WpT_hi, bp, buf0);
  // xl = x @ Wg   (overwrites imgT, dead)
  gemm1p<<<2048, 256, 0, stream>>>(buf0, WgT_hi, nullptr, buf1);

  float* outg = (float*)d_out;
  float* outa = (float*)d_out + (size_t)NNODE*CC;
  fused_agg<<<NNODE/8, 256, 0, stream>>>(buf1, buf0, cur, dinv, bucket,
                                         bg, lng, lnb, dq, outg, logits);
  softmax_rows<<<256, 256, 0, stream>>>(logits, outa);
}

// Round 11
// 228.795 us; speedup vs baseline: 1.4848x; 1.0603x over previous
//
#include <hip/hip_runtime.h>
#include <hip/hip_bf16.h>

typedef unsigned short u16;
typedef __attribute__((ext_vector_type(8))) short short8;
typedef __attribute__((ext_vector_type(16))) float f32x16;

#define AS1C(p) ((const __attribute__((address_space(1))) void*)(p))
#define AS3(p)  ((__attribute__((address_space(3))) void*)(p))

constexpr int CC    = 256;      // channels
constexpr int HWSZ  = 4096;     // H*W
constexpr int NNODE = 131072;   // B*H*W
constexpr int EEDG  = 524288;   // edges
constexpr int CAP   = 32;      // per-node bucket capacity

__device__ __forceinline__ float bf2f(u16 h){ unsigned u = ((unsigned)h)<<16; float f; __builtin_memcpy(&f,&u,4); return f; }
__device__ __forceinline__ u16 f2bf(float f){ unsigned u; __builtin_memcpy(&u,&f,4); return (u16)((u + 0x7FFFu + ((u>>16)&1u))>>16); }

// RNE pack of two f32 -> one u32 of 2 bf16 (low = a). Compiler emits v_cvt_pk_bf16_f32.
__device__ __forceinline__ unsigned pkbf(float a, float b){
  float2 t; t.x = a; t.y = b;
  __hip_bfloat162 h = __float22bfloat162_rn(t);
  unsigned u; __builtin_memcpy(&u,&h,4); return u;
}

// tanh-form GELU via native exp (max abs err vs exact ~3e-4)
__device__ __forceinline__ float gelu_fast(float v){
  float y = 0.7978845608f*(v + 0.044715f*v*v*v);
  float e = __expf(2.0f*y);
  float r = __builtin_amdgcn_rcpf(e + 1.0f);
  return 0.5f*v*(2.0f - 2.0f*r);
}

__device__ __forceinline__ void unpack8(uint4 q, float f[8]){
  unsigned w0=q.x,w1=q.y,w2=q.z,w3=q.w;
  unsigned l0=w0<<16, h0=w0&0xffff0000u, l1=w1<<16, h1=w1&0xffff0000u;
  unsigned l2=w2<<16, h2=w2&0xffff0000u, l3=w3<<16, h3=w3&0xffff0000u;
  __builtin_memcpy(&f[0],&l0,4); __builtin_memcpy(&f[1],&h0,4);
  __builtin_memcpy(&f[2],&l1,4); __builtin_memcpy(&f[3],&h1,4);
  __builtin_memcpy(&f[4],&l2,4); __builtin_memcpy(&f[5],&h2,4);
  __builtin_memcpy(&f[6],&l3,4); __builtin_memcpy(&f[7],&h3,4);
}

// ---------------- fp32 64x64 tiled transpose (weights only) ----------------
__global__ __launch_bounds__(256) void transpose_split(const float* __restrict__ src,
                                                       u16* __restrict__ dhi, u16* __restrict__ dlo,
                                                       int R, int Ccols, size_t sb_in, size_t sb_out)
{
  __shared__ float t[64][65];
  const float* s = src + blockIdx.z*sb_in + (size_t)(blockIdx.y*64)*Ccols + blockIdx.x*64;
  size_t obase   = blockIdx.z*sb_out + (size_t)(blockIdx.x*64)*R + blockIdx.y*64;
  int tid = threadIdx.x;
  for (int i=0;i<4;++i){
    int idx = i*256 + tid;
    int r = idx>>4, q = idx&15;
    float4 v = *(const float4*)(s + (size_t)r*Ccols + q*4);
    t[r][q*4+0]=v.x; t[r][q*4+1]=v.y; t[r][q*4+2]=v.z; t[r][q*4+3]=v.w;
  }
  __syncthreads();
  for (int i=0;i<2;++i){
    int idx = i*256 + tid;
    int rr = idx>>3, ch = idx&7;
    u16 hi[8], lo[8];
    for (int j=0;j<8;++j){
      float f = t[ch*8+j][rr];
      u16 h = f2bf(f); hi[j] = h;
      lo[j] = f2bf(f - bf2f(h));
    }
    *(uint4*)(dhi + obase + (size_t)rr*R + ch*8) = *(uint4*)hi;
    if (dlo) *(uint4*)(dlo + obase + (size_t)rr*R + ch*8) = *(uint4*)lo;
  }
}

// ---------------- GEMM1 with fused transpose: x = imgT @ Wp + bp ----------------
// BM=64 nodes, BN=256. A staged global(fp32 [C,HW]) -> reg -> cvt_pk bf16 ->
// ds_write_b64 into the SAME XOR-chunk-swizzled [64][32] layout the proven
// fragment reader uses. B via global_load_lds. 2-phase dbuf, 1 barrier/step.
__global__ __launch_bounds__(256,3) void gemm_t1(const float* __restrict__ img,
                                                 const u16* __restrict__ Bt,
                                                 const float* __restrict__ bias,
                                                 u16* __restrict__ C)
{
  __shared__ u16 As[2][64*32];
  __shared__ u16 Bs[2][256*32];
  const int tid = threadIdx.x, wid = tid>>6, lane = tid&63;
  const int row0 = blockIdx.x*64;
  const int bb = row0>>12, hw0 = row0&4095;
  const float* abase = img + (size_t)bb*CC*HWSZ + hw0;
  const int l31 = lane&31, lh = lane>>5;
  const int mpr = l31;                 // node-pair index: nodes 2mpr, 2mpr+1
  const int cb  = wid*8 + lh*4;        // channel base within K-step (0..28)
  const int cs  = wid ^ (mpr&3);       // swizzled chunk (both nodes share n>>1 = mpr)
  const int wa0 = (2*mpr  )*32 + cs*8 + lh*4;   // u16 index of 8B run, node even
  const int wa1 = (2*mpr+1)*32 + cs*8 + lh*4;   // node odd

  f32x16 acc[2][2];
  #pragma unroll
  for (int i=0;i<2;++i)
    #pragma unroll
    for (int j=0;j<2;++j)
      #pragma unroll
      for (int e=0;e<16;++e) acc[i][j][e]=0.f;

  float2 ar[4];

#define LOADA(kt)                                                                      \
  { _Pragma("unroll")                                                                  \
    for (int i=0;i<4;++i)                                                              \
      ar[i] = *(const float2*)(abase + (size_t)((kt)+cb+i)*HWSZ + 2*mpr); }

#define WRITEA(buf)                                                                    \
  { uint2 p0, p1;                                                                      \
    p0.x = pkbf(ar[0].x, ar[1].x); p0.y = pkbf(ar[2].x, ar[3].x);                      \
    p1.x = pkbf(ar[0].y, ar[1].y); p1.y = pkbf(ar[2].y, ar[3].y);                      \
    *(uint2*)&As[buf][wa0] = p0;                                                       \
    *(uint2*)&As[buf][wa1] = p1; }

#define STAGE_B(buf, kt)                                                               \
  { _Pragma("unroll")                                                                  \
    for (int it=0; it<4; ++it){                                                        \
      int qb = (it*4+wid)*64;                                                          \
      int q  = qb + lane;                                                              \
      int m  = q>>2, sc = q&3;                                                         \
      int gs = sc ^ ((m>>1)&3);                                                        \
      __builtin_amdgcn_global_load_lds(AS1C(Bt + (size_t)m*256 + (kt) + gs*8),         \
                                       AS3(&Bs[buf][qb*8]), 16, 0, 0); } }

  LOADA(0)
  STAGE_B(0, 0)
  WRITEA(0)
  asm volatile("s_waitcnt vmcnt(0)" ::: "memory");
  __syncthreads();

  for (int t=0; t<8; ++t) {
    int cur = t&1;
    if (t<7) { LOADA((t+1)*32) STAGE_B(cur^1, (t+1)*32) }

    short8 af[2][2], bfr[2][2];
    #pragma unroll
    for (int fm=0; fm<2; ++fm)
      #pragma unroll
      for (int kh=0; kh<2; ++kh) {
        int row = fm*32 + l31;
        int sa  = (kh*2 + lh) ^ ((row>>1)&3);
        af[fm][kh] = *(const short8*)&As[cur][row*32 + sa*8];
      }
    #pragma unroll
    for (int fn=0; fn<2; ++fn)
      #pragma unroll
      for (int kh=0; kh<2; ++kh) {
        int col = wid*64 + fn*32 + l31;
        int sb  = (kh*2 + lh) ^ ((col>>1)&3);
        bfr[fn][kh] = *(const short8*)&Bs[cur][col*32 + sb*8];
      }
    #pragma unroll
    for (int kh=0; kh<2; ++kh)
      #pragma unroll
      for (int fm=0; fm<2; ++fm)
        #pragma unroll
        for (int fn=0; fn<2; ++fn)
          acc[fm][fn] = __builtin_amdgcn_mfma_f32_32x32x16_bf16(af[fm][kh], bfr[fn][kh], acc[fm][fn], 0, 0, 0);

    if (t<7) WRITEA(cur^1)                      // pack t+1's tile (waits its vmcnt)
    asm volatile("s_waitcnt vmcnt(0)" ::: "memory");  // B DMA for t+1 complete
    __syncthreads();
  }
#undef STAGE_B
#undef WRITEA
#undef LOADA

  #pragma unroll
  for (int fn=0; fn<2; ++fn) {
    int col = wid*64 + fn*32 + l31;
    float bv = bias ? bias[col] : 0.f;
    #pragma unroll
    for (int fm=0; fm<2; ++fm) {
      int rbase = row0 + fm*32 + 4*lh;
      #pragma unroll
      for (int reg=0; reg<16; ++reg) {
        int row = rbase + (reg&3) + 8*(reg>>2);
        C[(size_t)row*256 + col] = f2bf(acc[fm][fn][reg] + bv);
      }
    }
  }
}

// ---------------- GEMM2: xl = x @ Wg  (BM=64, BN=256, R8-proven) ----------------
__global__ __launch_bounds__(256,3) void gemm1p(const u16* __restrict__ A,
                                                const u16* __restrict__ Bt,
                                                const float* __restrict__ bias,
                                                u16* __restrict__ C)
{
  __shared__ u16 As[2][64*32];
  __shared__ u16 Bs[2][256*32];
  const int tid = threadIdx.x, wid = tid>>6, lane = tid&63;
  const int row0 = blockIdx.x*64;
  const int l31 = lane&31, lh = lane>>5;

  f32x16 acc[2][2];
  #pragma unroll
  for (int i=0;i<2;++i)
    #pragma unroll
    for (int j=0;j<2;++j)
      #pragma unroll
      for (int e=0;e<16;++e) acc[i][j][e]=0.f;

#define STAGE_AB(buf, kt)                                                              \
  {                                                                                    \
    {                                                                                  \
      int qb = wid*64;                                                                 \
      int q  = qb + lane;                                                              \
      int m  = q>>2, sc = q&3;                                                         \
      int gs = sc ^ ((m>>1)&3);                                                        \
      __builtin_amdgcn_global_load_lds(AS1C(A + (size_t)(row0+m)*256 + (kt) + gs*8),   \
                                       AS3(&As[buf][qb*8]), 16, 0, 0);                 \
    }                                                                                  \
    _Pragma("unroll")                                                                  \
    for (int it=0; it<4; ++it){                                                        \
      int qb = (it*4+wid)*64;                                                          \
      int q  = qb + lane;                                                              \
      int m  = q>>2, sc = q&3;                                                         \
      int gs = sc ^ ((m>>1)&3);                                                        \
      __builtin_amdgcn_global_load_lds(AS1C(Bt + (size_t)m*256 + (kt) + gs*8),         \
                                       AS3(&Bs[buf][qb*8]), 16, 0, 0);                 \
    }                                                                                  \
  }

  STAGE_AB(0, 0)
  asm volatile("s_waitcnt vmcnt(0)" ::: "memory");
  __syncthreads();

  for (int t=0; t<8; ++t) {
    int cur = t&1;
    if (t<7) STAGE_AB(cur^1, (t+1)*32)

    short8 af[2][2], bfr[2][2];
    #pragma unroll
    for (int fm=0; fm<2; ++fm)
      #pragma unroll
      for (int kh=0; kh<2; ++kh) {
        int row = fm*32 + l31;
        int sa  = (kh*2 + lh) ^ ((row>>1)&3);
        af[fm][kh] = *(const short8*)&As[cur][row*32 + sa*8];
      }
    #pragma unroll
    for (int fn=0; fn<2; ++fn)
      #pragma unroll
      for (int kh=0; kh<2; ++kh) {
        int col = wid*64 + fn*32 + l31;
        int sb  = (kh*2 + lh) ^ ((col>>1)&3);
        bfr[fn][kh] = *(const short8*)&Bs[cur][col*32 + sb*8];
      }
    #pragma unroll
    for (int kh=0; kh<2; ++kh)
      #pragma unroll
      for (int fm=0; fm<2; ++fm)
        #pragma unroll
        for (int fn=0; fn<2; ++fn)
          acc[fm][fn] = __builtin_amdgcn_mfma_f32_32x32x16_bf16(af[fm][kh], bfr[fn][kh], acc[fm][fn], 0, 0, 0);
    asm volatile("s_waitcnt vmcnt(0)" ::: "memory");
    __syncthreads();
  }
#undef STAGE_AB

  #pragma unroll
  for (int fn=0; fn<2; ++fn) {
    int col = wid*64 + fn*32 + l31;
    float bv = bias ? bias[col] : 0.f;
    #pragma unroll
    for (int fm=0; fm<2; ++fm) {
      int rbase = row0 + fm*32 + 4*lh;
      #pragma unroll
      for (int reg=0; reg<16; ++reg) {
        int row = rbase + (reg&3) + 8*(reg>>2);
        C[(size_t)row*256 + col] = f2bf(acc[fm][fn][reg] + bv);
      }
    }
  }
}

// ---------------- graph prep ----------------
__global__ void fill_all(const int* __restrict__ row, const int* __restrict__ col,
                         int* __restrict__ cur, int* __restrict__ bucket){
  int e = blockIdx.x*256 + threadIdx.x;
  if (e >= EEDG) return;
  int c = col[e];
  int s = atomicAdd(&cur[c], 1);
  if (s < CAP) bucket[(size_t)c*CAP + s] = row[e];
}
__global__ void calc_dinv(const int* __restrict__ cnt, float* __restrict__ dinv){
  int n = blockIdx.x*256 + threadIdx.x;
  if (n < NNODE) dinv[n] = rsqrtf((float)cnt[n] + 1.0f);
}

// ---------------- fused: aggregate + bg + GELU + residual + LN + head logits ----------------
__global__ __launch_bounds__(256) void fused_agg(
    const u16* __restrict__ xl, const u16* __restrict__ xhi,
    const int* __restrict__ cnt, const float* __restrict__ dinv, const int* __restrict__ bucket,
    const float* __restrict__ bgv, const float* __restrict__ gam, const float* __restrict__ bet,
    const float* __restrict__ qv, float* __restrict__ outg, float* __restrict__ logits)
{
  const int wid = threadIdx.x>>6, lane = threadIdx.x&63;
  const int half = lane>>5, sl = lane&31;
  const int n = blockIdx.x*8 + wid*2 + half;
  const int c0 = sl*8;
  const float dn = dinv[n];
  int lim = cnt[n]; if (lim > CAP) lim = CAP;

  int rl = bucket[(size_t)n*CAP + sl];
  if (sl >= lim) rl = n;                 // sanitize poison slots
  float wl = (sl < lim) ? dinv[rl]*dn : 0.0f;

  uint4 qh = *(const uint4*)(xhi + (size_t)n*256 + c0);

  float a[8];
  {
    uint4 q = *(const uint4*)(xl + (size_t)n*256 + c0);
    unpack8(q, a);
    float wself = dn*dn;
    #pragma unroll
    for (int j=0;j<8;++j) a[j] *= wself;
  }

  int limR = (lim + 3) & ~3;
  for (int s=0; s<limR; s+=4) {
    int b0 = half*32 + s;
    int  r0 = __shfl(rl, b0),   r1 = __shfl(rl, b0+1);
    int  r2 = __shfl(rl, b0+2), r3 = __shfl(rl, b0+3);
    float w0 = __shfl(wl, b0),   w1 = __shfl(wl, b0+1);
    float w2 = __shfl(wl, b0+2), w3 = __shfl(wl, b0+3);
    uint4 q0 = *(const uint4*)(xl + (size_t)r0*256 + c0);
    uint4 q1 = *(const uint4*)(xl + (size_t)r1*256 + c0);
    uint4 q2 = *(const uint4*)(xl + (size_t)r2*256 + c0);
    uint4 q3 = *(const uint4*)(xl + (size_t)r3*256 + c0);
    float f0[8], f1[8], f2[8], f3[8];
    unpack8(q0, f0); unpack8(q1, f1); unpack8(q2, f2); unpack8(q3, f3);
    #pragma unroll
    for (int j=0;j<8;++j) a[j] += f0[j]*w0 + f1[j]*w1 + f2[j]*w2 + f3[j]*w3;
  }

  float xv[8];
  unpack8(qh, xv);

  float4 b0v = *(const float4*)(bgv + c0), b1v = *(const float4*)(bgv + c0 + 4);
  float bgs[8] = {b0v.x,b0v.y,b0v.z,b0v.w,b1v.x,b1v.y,b1v.z,b1v.w};
  float g[8];
  float s1 = 0.f, s2 = 0.f;
  #pragma unroll
  for (int j=0;j<8;++j){
    g[j] = gelu_fast(a[j] + bgs[j]) + xv[j];
    s1 += g[j]; s2 += g[j]*g[j];
  }
  #pragma unroll
  for (int off=16; off; off>>=1){ s1 += __shfl_xor(s1, off); s2 += __shfl_xor(s2, off); }
  float mu  = s1*(1.0f/256.0f);
  float var = s2*(1.0f/256.0f) - mu*mu;
  float inv = rsqrtf(var + 1e-5f);

  float4 g0 = *(const float4*)(gam + c0), g1 = *(const float4*)(gam + c0 + 4);
  float4 e0 = *(const float4*)(bet + c0), e1 = *(const float4*)(bet + c0 + 4);
  float gms[8] = {g0.x,g0.y,g0.z,g0.w,g1.x,g1.y,g1.z,g1.w};
  float bts[8] = {e0.x,e0.y,e0.z,e0.w,e1.x,e1.y,e1.z,e1.w};
  float y[8];
  #pragma unroll
  for (int j=0;j<8;++j) y[j] = (g[j]-mu)*inv*gms[j] + bts[j];

  float4 o0 = {y[0],y[1],y[2],y[3]}, o1 = {y[4],y[5],y[6],y[7]};
  *reinterpret_cast<float4*>(outg + (size_t)n*256 + c0)     = o0;
  *reinterpret_cast<float4*>(outg + (size_t)n*256 + c0 + 4) = o1;

  float4 q0 = *(const float4*)(qv + c0), q1 = *(const float4*)(qv + c0 + 4);
  float qs[8] = {q0.x,q0.y,q0.z,q0.w,q1.x,q1.y,q1.z,q1.w};
  float dq = 0.f;
  #pragma unroll
  for (int j=0;j<8;++j) dq += y[j]*qs[j];
  dq += __shfl_xor(dq,1); dq += __shfl_xor(dq,2);
  if ((sl&3)==0){
    int b = n>>12, p = n&4095, h = sl>>2;
    logits[(size_t)(b*8+h)*4096 + p] = dq*10.0f;   // 1/TEMPERATURE
  }
}

// ---------------- row softmax over 4096 (fp32 in/out) ----------------
__global__ __launch_bounds__(256) void softmax_rows(const float* __restrict__ logits, float* __restrict__ outa){
  int r = blockIdx.x;
  const float* p = logits + (size_t)r*4096;
  int tid = threadIdx.x;
  int wid = tid>>6, lane = tid&63;
  __shared__ float redm[4];
  __shared__ float reds[4];
  float v[16];
  float mx = -1e30f;
  for (int i=0;i<16;++i){ v[i] = p[tid + i*256]; mx = fmaxf(mx, v[i]); }
  for (int off=32; off; off>>=1) mx = fmaxf(mx, __shfl_xor(mx, off));
  if (lane==0) redm[wid]=mx;
  __syncthreads();
  mx = fmaxf(fmaxf(redm[0],redm[1]), fmaxf(redm[2],redm[3]));
  float sum = 0.f;
  for (int i=0;i<16;++i){ v[i] = expf(v[i]-mx); sum += v[i]; }
  for (int off=32; off; off>>=1) sum += __shfl_xor(sum, off);
  if (lane==0) reds[wid]=sum;
  __syncthreads();
  sum = reds[0]+reds[1]+reds[2]+reds[3];
  float rinv = 1.0f/sum;
  for (int i=0;i<16;++i) outa[(size_t)r*4096 + tid + i*256] = v[i]*rinv;
}

extern "C" void kernel_launch(void* const* d_in, const int* in_sizes, int n_in,
                              void* d_out, int out_size, void* d_ws, size_t ws_size,
                              hipStream_t stream)
{
  const float* img  = (const float*)d_in[0];
  const int* edges  = (const int*)d_in[1];   // [2][E] int32: row=edges, col=edges+E
  const float* Wp   = (const float*)d_in[2];
  const float* bp   = (const float*)d_in[3];
  const float* Wg   = (const float*)d_in[4];
  const float* bg   = (const float*)d_in[5];
  const float* lng  = (const float*)d_in[6];
  const float* lnb  = (const float*)d_in[7];
  const float* dq   = (const float*)d_in[8];
  char* ws = (char*)d_ws;

  constexpr size_t REG  = (size_t)NNODE*CC*2;                                   // 67,108,864
  constexpr size_t WTS  = 2u*131072;
  constexpr size_t GBLK = 524288u*2 + (size_t)NNODE*CAP*4 + (size_t)256*4096*4; // ~21.8 MB
  if (ws_size < 2*REG + WTS + GBLK) return;

  u16* buf0 = (u16*)(ws + 0);        // x_hi
  u16* buf1 = (u16*)(ws + REG);      // xl
  char* wts  = ws + 2*REG;
  char* gblk = wts + WTS;

  u16* WpT_hi = (u16*)(wts);
  u16* WgT_hi = (u16*)(wts + 131072);
  int*   cur    = (int*)(gblk);
  float* dinv   = (float*)(gblk + 524288);
  int*   bucket = (int*)(gblk + 1048576);
  float* logits = (float*)(gblk + 1048576 + (size_t)NNODE*CAP*4);

  // weight transposes (tiny, hi only)
  transpose_split<<<dim3(4,4,1), 256, 0, stream>>>(Wp, WpT_hi, nullptr, 256, 256, 0, 0);
  transpose_split<<<dim3(4,4,1), 256, 0, stream>>>(Wg, WgT_hi, nullptr, 256, 256, 0, 0);

  // graph prep
  hipMemsetAsync(cur, 0, 524288, stream);
  fill_all <<<2048, 256, 0, stream>>>(edges, edges+EEDG, cur, bucket);
  calc_dinv<<<512,  256, 0, stream>>>(cur, dinv);

  // x = imgT @ Wp + bp   (transpose fused via reg->LDS staging)
  gemm_t1<<<2048, 256, 0, stream>>>(img, WpT_hi, bp, buf0);
  // xl = x @ Wg
  gemm1p<<<2048, 256, 0, stream>>>(buf0, WgT_hi, nullptr, buf1);

  float* outg = (float*)d_out;
  float* outa = (float*)d_out + (size_t)NNODE*CC;
  fused_agg<<<NNODE/8, 256, 0, stream>>>(buf1, buf0, cur, dinv, bucket,
                                         bg, lng, lnb, dq, outg, logits);
  softmax_rows<<<256, 256, 0, stream>>>(logits, outa);
}